// Round 10
// baseline (345.339 us; speedup 1.0000x reference)
//
#include <hip/hip_runtime.h>
#include <hip/hip_bf16.h>

#define HID 256
#define IND 21
#define PB 6400      // edges per block in k_part / bhist
#define MAXB 512     // max buckets (N <= 131072)

typedef short short8 __attribute__((ext_vector_type(8)));
typedef float floatx16 __attribute__((ext_vector_type(16)));
typedef float floatx2 __attribute__((ext_vector_type(2)));

__device__ inline unsigned short f2bf(float f) {
  __hip_bfloat16 h = __float2bfloat16(f);  // RNE
  union { __hip_bfloat16 h; unsigned short u; } c;
  c.h = h;
  return c.u;
}

// pack float2 -> 2 bf16 by truncation (exact for values that came from fp8)
__device__ inline unsigned int pk_bf16_trunc(floatx2 p) {
  union { float f; unsigned int u; } a, b;
  a.f = p.x; b.f = p.y;
  return (b.u & 0xffff0000u) | (a.u >> 16);
}

// accumulate 8 fp8 bytes into 4 packed-f32 accumulators
__device__ inline void acc8p(uint2 v, floatx2* a) {
  a[0] += __builtin_amdgcn_cvt_pk_f32_fp8((int)v.x, false);
  a[1] += __builtin_amdgcn_cvt_pk_f32_fp8((int)v.x, true);
  a[2] += __builtin_amdgcn_cvt_pk_f32_fp8((int)v.y, false);
  a[3] += __builtin_amdgcn_cvt_pk_f32_fp8((int)v.y, true);
}

__device__ inline short8 mk_s8(unsigned a, unsigned b, unsigned c, unsigned d) {
  union { uint4 u; short8 s; } x; x.u = make_uint4(a, b, c, d); return x.s;
}
__device__ inline short8 u4_s8(uint4 v) {
  union { uint4 u; short8 s; } x; x.u = v; return x.s;
}

// decode 8 fp8 bytes (uint2) -> short8 of bf16 (exact)
__device__ inline short8 dec8(uint2 v) {
  unsigned w0 = pk_bf16_trunc(__builtin_amdgcn_cvt_pk_f32_fp8((int)v.x, false));
  unsigned w1 = pk_bf16_trunc(__builtin_amdgcn_cvt_pk_f32_fp8((int)v.x, true));
  unsigned w2 = pk_bf16_trunc(__builtin_amdgcn_cvt_pk_f32_fp8((int)v.y, false));
  unsigned w3 = pk_bf16_trunc(__builtin_amdgcn_cvt_pk_f32_fp8((int)v.y, true));
  return mk_s8(w0, w1, w2, w3);
}

// ---------------------------------------------------------------------------
// fused front kernel: [0,G1) linear_in | [G1,G1+256) wconv | rest bhist
// wconv writes B in MFMA-fragment-linear order for 32x32x16:
//   Bf16[ ((c*8+ct)*64 + lane)*8 + j ] = W[k][n],
//   k = c*16 + (lane>>5)*8 + j, n = ct*32 + (lane&31)
// ---------------------------------------------------------------------------
__global__ __launch_bounds__(256) void k_front(
    const float* __restrict__ ns, const float* __restrict__ Win,
    const float* __restrict__ bin, unsigned int* __restrict__ xq,
    const float* __restrict__ Wself, const float* __restrict__ Wnei,
    unsigned short* __restrict__ Bf16,
    const int* __restrict__ dst, int* __restrict__ bcnt,
    int N, int E, int nb2, int G1) {
  int blk = blockIdx.x;
  int tid = threadIdx.x;
  if (blk < G1) {
    __shared__ float s[8][IND];
    __shared__ float fx[8][257];
    int nb = blk * 8;
    if (tid < 8 * IND) {
      int idx = nb * IND + tid;
      s[tid / IND][tid % IND] = (idx < N * IND) ? ns[idx] : 0.f;
    }
    float w[IND];
#pragma unroll
    for (int k = 0; k < IND; k++) w[k] = Win[k * HID + tid];
    float b = bin[tid];
    __syncthreads();
#pragma unroll
    for (int j = 0; j < 8; j++) {
      float acc = b;
#pragma unroll
      for (int k = 0; k < IND; k++) acc += s[j][k] * w[k];
      fx[j][tid] = acc > 0.f ? acc : 0.f;
    }
    __syncthreads();
#pragma unroll
    for (int t = 0; t < 2; t++) {
      int wi = tid + t * 256;
      int j = wi >> 6, cw = wi & 63;
      int node = nb + j;
      if (node < N) {
        const float* fp = &fx[j][cw * 4];
        int lo = __builtin_amdgcn_cvt_pk_fp8_f32(fp[0], fp[1], 0, false);
        int full = __builtin_amdgcn_cvt_pk_fp8_f32(fp[2], fp[3], lo, true);
        xq[(size_t)node * 64 + cw] = (unsigned int)full;
      }
    }
  } else if (blk < G1 + 256) {
    int n = blk - G1;           // output column 0..255
    int ct = n >> 5, l5 = n & 31;
#pragma unroll
    for (int t = 0; t < 2; t++) {
      int k = tid + t * 256;    // 0..511
      float v = (k < HID) ? Wself[k * HID + n] : Wnei[(k - HID) * HID + n];
      int c = k >> 4, kin = k & 15;
      int lane = (kin >> 3) * 32 + l5;
      int j = kin & 7;
      Bf16[(size_t)((c * 8 + ct) * 64 + lane) * 8 + j] = f2bf(v);
    }
  } else {
    __shared__ int lh[MAXB];
    int e0 = (blk - G1 - 256) * PB;
    for (int b = tid; b < nb2; b += 256) lh[b] = 0;
    __syncthreads();
    int c = min(PB, E - e0);
    for (int i = tid; i < c; i += 256) atomicAdd(&lh[dst[e0 + i] >> 8], 1);
    __syncthreads();
    for (int b = tid; b < nb2; b += 256)
      if (lh[b]) atomicAdd(&bcnt[b], lh[b]);
  }
}

__global__ __launch_bounds__(512) void k_bscan(
    const int* __restrict__ bcnt, int* __restrict__ bbase, int* __restrict__ bcur,
    int* __restrict__ row_start, int E, int N, int nb2) {
  __shared__ int ts[512];
  int tid = threadIdx.x;
  int v = (tid < nb2) ? bcnt[tid] : 0;
  ts[tid] = v;
  __syncthreads();
  for (int off = 1; off < 512; off <<= 1) {
    int t = (tid >= off) ? ts[tid - off] : 0;
    __syncthreads();
    ts[tid] += t;
    __syncthreads();
  }
  if (tid < nb2) { bbase[tid] = ts[tid] - v; bcur[tid] = ts[tid] - v; }
  if (tid == 0) { bbase[nb2] = E; row_start[N] = E; }
}

// partition edges into per-bucket regions of ebuf (bucket = dst>>8).
// ebuf entry packed: (src << 8) | (dst & 255) -- 4 B/edge.
__global__ __launch_bounds__(256) void k_part(
    const int* __restrict__ src, const int* __restrict__ dst,
    int* __restrict__ bcur, unsigned int* __restrict__ ebuf, int E, int nb2) {
  __shared__ int lh[MAXB];
  int tid = threadIdx.x;
  int e0 = blockIdx.x * PB;
  for (int b = tid; b < nb2; b += 256) lh[b] = 0;
  __syncthreads();
  int cnt = min(PB, E - e0);
  for (int i = tid; i < cnt; i += 256) atomicAdd(&lh[dst[e0 + i] >> 8], 1);
  __syncthreads();
  for (int b = tid; b < nb2; b += 256) {
    int c = lh[b];
    lh[b] = (c > 0) ? atomicAdd(&bcur[b], c) : 0;
  }
  __syncthreads();
  for (int i = tid; i < cnt; i += 256) {
    int s = src[e0 + i];
    int d = dst[e0 + i];
    int pos = atomicAdd(&lh[d >> 8], 1);
    ebuf[pos] = ((unsigned)s << 8) | ((unsigned)d & 255u);
  }
}

// one block per bucket: LDS count + scan -> row_start; LDS cursors -> csr.
__global__ __launch_bounds__(256) void k_fill2(
    const unsigned int* __restrict__ ebuf, const int* __restrict__ bbase,
    int* __restrict__ row_start, int* __restrict__ csr, int N) {
  __shared__ int lcnt[256];
  __shared__ int lcur[256];
  __shared__ int ts[256];
  int b = blockIdx.x;
  int tid = threadIdx.x;
  int start = bbase[b], end = bbase[b + 1];
  lcnt[tid] = 0;
  __syncthreads();
  for (int i = start + tid; i < end; i += 256)
    atomicAdd(&lcnt[ebuf[i] & 255u], 1);
  __syncthreads();
  int v = lcnt[tid];
  ts[tid] = v;
  __syncthreads();
  for (int off = 1; off < 256; off <<= 1) {
    int t = (tid >= off) ? ts[tid - off] : 0;
    __syncthreads();
    ts[tid] += t;
    __syncthreads();
  }
  int excl = start + ts[tid] - v;
  int node = (b << 8) + tid;
  if (node < N) row_start[node] = excl;
  lcur[tid] = excl;
  __syncthreads();
  for (int i = start + tid; i < end; i += 256) {
    unsigned int e = ebuf[i];
    int pos = atomicAdd(&lcur[e & 255u], 1);
    csr[pos] = (int)(e >> 8);
  }
}

// ---------------------------------------------------------------------------
// k_agg: one wave per node; fp8 gather, 8 edges/iter, packed-f32 adds.
// ---------------------------------------------------------------------------
__global__ __launch_bounds__(256) void k_agg(
    const uint2* __restrict__ xq, const int* __restrict__ csr,
    const int* __restrict__ row_start, uint2* __restrict__ aggq, int N) {
  int wid = (int)((blockIdx.x * (unsigned)blockDim.x + threadIdx.x) >> 6);
  int lane = threadIdx.x & 63;
  int half = lane >> 5;
  int l32 = lane & 31;
  if (wid >= N) return;
  int start = row_start[wid];
  int end = row_start[wid + 1];
  int c = end - start;
  floatx2 a[4], b[4], d[4], e[4];
#pragma unroll
  for (int j = 0; j < 4; j++) {
    a[j] = (floatx2){0.f, 0.f}; b[j] = (floatx2){0.f, 0.f};
    d[j] = (floatx2){0.f, 0.f}; e[j] = (floatx2){0.f, 0.f};
  }
  int i = 0;
  for (; i + 8 <= c; i += 8) {
    int s0 = csr[start + i + half];
    int s1 = csr[start + i + 2 + half];
    int s2 = csr[start + i + 4 + half];
    int s3 = csr[start + i + 6 + half];
    uint2 v0 = xq[(size_t)s0 * 32 + l32];
    uint2 v1 = xq[(size_t)s1 * 32 + l32];
    uint2 v2 = xq[(size_t)s2 * 32 + l32];
    uint2 v3 = xq[(size_t)s3 * 32 + l32];
    acc8p(v0, a); acc8p(v1, b); acc8p(v2, d); acc8p(v3, e);
  }
  for (; i + 2 <= c; i += 2) {
    int s0 = csr[start + i + half];
    uint2 v0 = xq[(size_t)s0 * 32 + l32];
    acc8p(v0, a);
  }
  if ((c & 1) && half == 0) {
    int s0 = csr[start + c - 1];
    uint2 v0 = xq[(size_t)s0 * 32 + l32];
    acc8p(v0, a);
  }
#pragma unroll
  for (int j = 0; j < 4; j++) a[j] += b[j] + d[j] + e[j];

  float f[8];
#pragma unroll
  for (int j = 0; j < 4; j++) { f[2 * j] = a[j].x; f[2 * j + 1] = a[j].y; }
#pragma unroll
  for (int j = 0; j < 8; j++) f[j] += __shfl_xor(f[j], 32);

  if (half == 0) {
    float inv = 1.0f / fmaxf((float)c, 1.0f);
#pragma unroll
    for (int j = 0; j < 8; j++) f[j] *= inv;
    int lo0 = __builtin_amdgcn_cvt_pk_fp8_f32(f[0], f[1], 0, false);
    int w0  = __builtin_amdgcn_cvt_pk_fp8_f32(f[2], f[3], lo0, true);
    int lo1 = __builtin_amdgcn_cvt_pk_fp8_f32(f[4], f[5], 0, false);
    int w1  = __builtin_amdgcn_cvt_pk_fp8_f32(f[6], f[7], lo1, true);
    aggq[(size_t)wid * 32 + l32] = make_uint2((unsigned)w0, (unsigned)w1);
  }
}

// ---------------------------------------------------------------------------
// k_h: gsum[c] += sum_rows relu( [x|agg] @ W + b )  -- wave-independent GEMM.
// No LDS staging, no K-loop barriers. Each wave owns 32 rows x 256 cols using
// mfma_f32_32x32x16_bf16: A-frag = 8 fp8 bytes direct global->VGPR (decoded
// to bf16, exact); B pre-swizzled fragment-linear (1 KB coalesced wave loads,
// L2-resident 256 KB). acc = 8 x floatx16 (128 VGPRs).
// C/D: col=lane&31, row=(reg&3)+8*(reg>>2)+4*(lane>>5)  [m74/m101 verified]
// ---------------------------------------------------------------------------
__global__ __launch_bounds__(256, 2) void k_h(
    const unsigned char* __restrict__ xq8, const unsigned char* __restrict__ aggq8,
    const uint4* __restrict__ Bf, const float* __restrict__ bself,
    const float* __restrict__ bnei, float* __restrict__ gsum, int N) {
  __shared__ float colsum[256];
  int tid = threadIdx.x;
  int lane = tid & 63;
  int w = tid >> 6;
  int l32 = lane & 31;
  int half = lane >> 5;
  int rowBase = blockIdx.x * 128 + w * 32;
  int row = rowBase + l32;
  if (row >= N) row = N - 1;

  colsum[tid] = 0.f;
  __syncthreads();

  floatx16 acc[8];
#pragma unroll
  for (int j = 0; j < 8; j++) acc[j] = (floatx16)(0.f);

  size_t aoff = (size_t)row * HID + half * 8;

  for (int c = 0; c < 32; c++) {
    const unsigned char* ab = (c < 16) ? xq8 : aggq8;
    uint2 va = *(const uint2*)(ab + aoff + (size_t)(c & 15) * 16);
    short8 af = dec8(va);
    const uint4* bp = Bf + (size_t)c * 512 + lane;   // c*8 frag-groups of 64
#pragma unroll
    for (int ct = 0; ct < 8; ct++) {
      short8 bf = u4_s8(bp[ct * 64]);
      acc[ct] = __builtin_amdgcn_mfma_f32_32x32x16_bf16(af, bf, acc[ct], 0, 0, 0);
    }
  }

  // epilogue: bias + relu + row-masked column sums
#pragma unroll
  for (int ct = 0; ct < 8; ct++) {
    int col = ct * 32 + l32;
    float bb = bself[col] + bnei[col];
    float psum = 0.f;
#pragma unroll
    for (int r = 0; r < 16; r++) {
      int rw = rowBase + (r & 3) + 8 * (r >> 2) + 4 * half;
      float v = acc[ct][r] + bb;
      v = v > 0.f ? v : 0.f;
      if (rw < N) psum += v;
    }
    atomicAdd(&colsum[col], psum);
  }
  __syncthreads();
  atomicAdd(&gsum[tid], colsum[tid]);
}

// ---------------------------------------------------------------------------
// k_out: out = (gsum / N) @ W_out + b_out   single block, 256 threads
// ---------------------------------------------------------------------------
__global__ __launch_bounds__(HID) void k_out(
    const float* __restrict__ gsum, const float* __restrict__ Wout,
    const float* __restrict__ bout, float* __restrict__ out, float invN) {
  __shared__ float g[HID];
  int c = threadIdx.x;
  g[c] = gsum[c] * invN;
  __syncthreads();
  float acc = bout[c];
#pragma unroll 8
  for (int k = 0; k < HID; k++) acc += g[k] * Wout[k * HID + c];
  out[c] = acc;
}

extern "C" void kernel_launch(void* const* d_in, const int* in_sizes, int n_in,
                              void* d_out, int out_size, void* d_ws, size_t ws_size,
                              hipStream_t stream) {
  const float* ns    = (const float*)d_in[0];
  const float* Win   = (const float*)d_in[1];
  const float* bin   = (const float*)d_in[2];
  const float* Wself = (const float*)d_in[3];
  const float* bself = (const float*)d_in[4];
  const float* Wnei  = (const float*)d_in[5];
  const float* bnei  = (const float*)d_in[6];
  const float* Wout  = (const float*)d_in[7];
  const float* bout  = (const float*)d_in[8];
  const int*   eidx  = (const int*)d_in[9];

  int N = in_sizes[0] / IND;
  int E = in_sizes[9] / 2;
  const int* src = eidx;
  const int* dst = eidx + E;
  int nb2 = (N + 255) >> 8;

  // ws layout: xq[N*64] uint | aggq[N*64] uint | Bf[32*8*64] uint4 (256 KB) |
  //   csr[E] i | ebuf[E] uint | row_start[N+1] i | bcnt | bbase | bcur | gsum
  unsigned int* xq    = (unsigned int*)d_ws;
  unsigned int* aggq  = xq + (size_t)N * 64;
  unsigned short* Bf16 = (unsigned short*)(aggq + (size_t)N * 64);
  int* csr       = (int*)(Bf16 + 256 * 512);
  unsigned int* ebuf = (unsigned int*)(csr + E);
  int* row_start = (int*)(ebuf + E);
  int* bcnt      = row_start + N + 1;
  int* bbase     = bcnt + MAXB;
  int* bcur      = bbase + MAXB + 1;
  float* gsum    = (float*)(bcur + MAXB);

  hipMemsetAsync(bcnt, 0, MAXB * sizeof(int), stream);
  hipMemsetAsync(gsum, 0, HID * sizeof(float), stream);

  int G1 = (N + 7) / 8;
  int pgrid = (E + PB - 1) / PB;
  k_front<<<G1 + 256 + pgrid, 256, 0, stream>>>(
      ns, Win, bin, xq, Wself, Wnei, Bf16, dst, bcnt, N, E, nb2, G1);

  k_bscan<<<1, 512, 0, stream>>>(bcnt, bbase, bcur, row_start, E, N, nb2);
  k_part<<<pgrid, 256, 0, stream>>>(src, dst, bcur, ebuf, E, nb2);
  k_fill2<<<nb2, 256, 0, stream>>>(ebuf, bbase, row_start, csr, N);

  int agrid = (N + 3) / 4;
  k_agg<<<agrid, 256, 0, stream>>>((const uint2*)xq, csr, row_start,
                                   (uint2*)aggq, N);

  int hgrid = (N + 127) / 128;
  k_h<<<hgrid, 256, 0, stream>>>((const unsigned char*)xq,
                                 (const unsigned char*)aggq,
                                 (const uint4*)Bf16, bself, bnei, gsum, N);

  k_out<<<1, HID, 0, stream>>>(gsum, Wout, bout, (float*)d_out, 1.0f / (float)N);
}

// Round 11
// 343.969 us; speedup vs baseline: 1.0040x; 1.0040x over previous
//
#include <hip/hip_runtime.h>
#include <hip/hip_bf16.h>

#define HID 256
#define IND 21
#define PB 6400      // edges per block in k_part / bhist
#define MAXB 512     // max buckets (N <= 131072)

typedef short short8 __attribute__((ext_vector_type(8)));
typedef float floatx16 __attribute__((ext_vector_type(16)));
typedef float floatx2 __attribute__((ext_vector_type(2)));

__device__ inline unsigned short f2bf(float f) {
  __hip_bfloat16 h = __float2bfloat16(f);  // RNE
  union { __hip_bfloat16 h; unsigned short u; } c;
  c.h = h;
  return c.u;
}

// pack float2 -> 2 bf16 by truncation (exact for values that came from fp8)
__device__ inline unsigned int pk_bf16_trunc(floatx2 p) {
  union { float f; unsigned int u; } a, b;
  a.f = p.x; b.f = p.y;
  return (b.u & 0xffff0000u) | (a.u >> 16);
}

// accumulate 8 fp8 bytes into 4 packed-f32 accumulators
__device__ inline void acc8p(uint2 v, floatx2* a) {
  a[0] += __builtin_amdgcn_cvt_pk_f32_fp8((int)v.x, false);
  a[1] += __builtin_amdgcn_cvt_pk_f32_fp8((int)v.x, true);
  a[2] += __builtin_amdgcn_cvt_pk_f32_fp8((int)v.y, false);
  a[3] += __builtin_amdgcn_cvt_pk_f32_fp8((int)v.y, true);
}

__device__ inline short8 mk_s8(unsigned a, unsigned b, unsigned c, unsigned d) {
  union { uint4 u; short8 s; } x; x.u = make_uint4(a, b, c, d); return x.s;
}
__device__ inline short8 u4_s8(uint4 v) {
  union { uint4 u; short8 s; } x; x.u = v; return x.s;
}

// decode 8 fp8 bytes (uint2) -> short8 of bf16 (exact)
__device__ inline short8 dec8(uint2 v) {
  unsigned w0 = pk_bf16_trunc(__builtin_amdgcn_cvt_pk_f32_fp8((int)v.x, false));
  unsigned w1 = pk_bf16_trunc(__builtin_amdgcn_cvt_pk_f32_fp8((int)v.x, true));
  unsigned w2 = pk_bf16_trunc(__builtin_amdgcn_cvt_pk_f32_fp8((int)v.y, false));
  unsigned w3 = pk_bf16_trunc(__builtin_amdgcn_cvt_pk_f32_fp8((int)v.y, true));
  return mk_s8(w0, w1, w2, w3);
}

// ---------------------------------------------------------------------------
// fused front kernel: [0,G1) linear_in | [G1,G1+256) wconv | rest bhist
// wconv writes B in MFMA-fragment-linear order for 32x32x16:
//   Bf16[ ((c*8+ct)*64 + lane)*8 + j ] = W[k][n],
//   k = c*16 + (lane>>5)*8 + j, n = ct*32 + (lane&31)
// ---------------------------------------------------------------------------
__global__ __launch_bounds__(256) void k_front(
    const float* __restrict__ ns, const float* __restrict__ Win,
    const float* __restrict__ bin, unsigned int* __restrict__ xq,
    const float* __restrict__ Wself, const float* __restrict__ Wnei,
    unsigned short* __restrict__ Bf16,
    const int* __restrict__ dst, int* __restrict__ bcnt,
    int N, int E, int nb2, int G1) {
  int blk = blockIdx.x;
  int tid = threadIdx.x;
  if (blk < G1) {
    __shared__ float s[8][IND];
    __shared__ float fx[8][257];
    int nb = blk * 8;
    if (tid < 8 * IND) {
      int idx = nb * IND + tid;
      s[tid / IND][tid % IND] = (idx < N * IND) ? ns[idx] : 0.f;
    }
    float w[IND];
#pragma unroll
    for (int k = 0; k < IND; k++) w[k] = Win[k * HID + tid];
    float b = bin[tid];
    __syncthreads();
#pragma unroll
    for (int j = 0; j < 8; j++) {
      float acc = b;
#pragma unroll
      for (int k = 0; k < IND; k++) acc += s[j][k] * w[k];
      fx[j][tid] = acc > 0.f ? acc : 0.f;
    }
    __syncthreads();
#pragma unroll
    for (int t = 0; t < 2; t++) {
      int wi = tid + t * 256;
      int j = wi >> 6, cw = wi & 63;
      int node = nb + j;
      if (node < N) {
        const float* fp = &fx[j][cw * 4];
        int lo = __builtin_amdgcn_cvt_pk_fp8_f32(fp[0], fp[1], 0, false);
        int full = __builtin_amdgcn_cvt_pk_fp8_f32(fp[2], fp[3], lo, true);
        xq[(size_t)node * 64 + cw] = (unsigned int)full;
      }
    }
  } else if (blk < G1 + 256) {
    int n = blk - G1;           // output column 0..255
    int ct = n >> 5, l5 = n & 31;
#pragma unroll
    for (int t = 0; t < 2; t++) {
      int k = tid + t * 256;    // 0..511
      float v = (k < HID) ? Wself[k * HID + n] : Wnei[(k - HID) * HID + n];
      int c = k >> 4, kin = k & 15;
      int lane = (kin >> 3) * 32 + l5;
      int j = kin & 7;
      Bf16[(size_t)((c * 8 + ct) * 64 + lane) * 8 + j] = f2bf(v);
    }
  } else {
    __shared__ int lh[MAXB];
    int e0 = (blk - G1 - 256) * PB;
    for (int b = tid; b < nb2; b += 256) lh[b] = 0;
    __syncthreads();
    int c = min(PB, E - e0);
    for (int i = tid; i < c; i += 256) atomicAdd(&lh[dst[e0 + i] >> 8], 1);
    __syncthreads();
    for (int b = tid; b < nb2; b += 256)
      if (lh[b]) atomicAdd(&bcnt[b], lh[b]);
  }
}

__global__ __launch_bounds__(512) void k_bscan(
    const int* __restrict__ bcnt, int* __restrict__ bbase, int* __restrict__ bcur,
    int* __restrict__ row_start, int E, int N, int nb2) {
  __shared__ int ts[512];
  int tid = threadIdx.x;
  int v = (tid < nb2) ? bcnt[tid] : 0;
  ts[tid] = v;
  __syncthreads();
  for (int off = 1; off < 512; off <<= 1) {
    int t = (tid >= off) ? ts[tid - off] : 0;
    __syncthreads();
    ts[tid] += t;
    __syncthreads();
  }
  if (tid < nb2) { bbase[tid] = ts[tid] - v; bcur[tid] = ts[tid] - v; }
  if (tid == 0) { bbase[nb2] = E; row_start[N] = E; }
}

// partition edges into per-bucket regions of ebuf (bucket = dst>>8).
// ebuf entry packed: (src << 8) | (dst & 255) -- 4 B/edge.
__global__ __launch_bounds__(256) void k_part(
    const int* __restrict__ src, const int* __restrict__ dst,
    int* __restrict__ bcur, unsigned int* __restrict__ ebuf, int E, int nb2) {
  __shared__ int lh[MAXB];
  int tid = threadIdx.x;
  int e0 = blockIdx.x * PB;
  for (int b = tid; b < nb2; b += 256) lh[b] = 0;
  __syncthreads();
  int cnt = min(PB, E - e0);
  for (int i = tid; i < cnt; i += 256) atomicAdd(&lh[dst[e0 + i] >> 8], 1);
  __syncthreads();
  for (int b = tid; b < nb2; b += 256) {
    int c = lh[b];
    lh[b] = (c > 0) ? atomicAdd(&bcur[b], c) : 0;
  }
  __syncthreads();
  for (int i = tid; i < cnt; i += 256) {
    int s = src[e0 + i];
    int d = dst[e0 + i];
    int pos = atomicAdd(&lh[d >> 8], 1);
    ebuf[pos] = ((unsigned)s << 8) | ((unsigned)d & 255u);
  }
}

// one block per bucket: LDS count + scan -> row_start; LDS cursors -> csr.
__global__ __launch_bounds__(256) void k_fill2(
    const unsigned int* __restrict__ ebuf, const int* __restrict__ bbase,
    int* __restrict__ row_start, int* __restrict__ csr, int N) {
  __shared__ int lcnt[256];
  __shared__ int lcur[256];
  __shared__ int ts[256];
  int b = blockIdx.x;
  int tid = threadIdx.x;
  int start = bbase[b], end = bbase[b + 1];
  lcnt[tid] = 0;
  __syncthreads();
  for (int i = start + tid; i < end; i += 256)
    atomicAdd(&lcnt[ebuf[i] & 255u], 1);
  __syncthreads();
  int v = lcnt[tid];
  ts[tid] = v;
  __syncthreads();
  for (int off = 1; off < 256; off <<= 1) {
    int t = (tid >= off) ? ts[tid - off] : 0;
    __syncthreads();
    ts[tid] += t;
    __syncthreads();
  }
  int excl = start + ts[tid] - v;
  int node = (b << 8) + tid;
  if (node < N) row_start[node] = excl;
  lcur[tid] = excl;
  __syncthreads();
  for (int i = start + tid; i < end; i += 256) {
    unsigned int e = ebuf[i];
    int pos = atomicAdd(&lcur[e & 255u], 1);
    csr[pos] = (int)(e >> 8);
  }
}

// ---------------------------------------------------------------------------
// k_agg: one wave per node; fp8 gather, 8 edges/iter, packed-f32 adds.
// ---------------------------------------------------------------------------
__global__ __launch_bounds__(256) void k_agg(
    const uint2* __restrict__ xq, const int* __restrict__ csr,
    const int* __restrict__ row_start, uint2* __restrict__ aggq, int N) {
  int wid = (int)((blockIdx.x * (unsigned)blockDim.x + threadIdx.x) >> 6);
  int lane = threadIdx.x & 63;
  int half = lane >> 5;
  int l32 = lane & 31;
  if (wid >= N) return;
  int start = row_start[wid];
  int end = row_start[wid + 1];
  int c = end - start;
  floatx2 a[4], b[4], d[4], e[4];
#pragma unroll
  for (int j = 0; j < 4; j++) {
    a[j] = (floatx2){0.f, 0.f}; b[j] = (floatx2){0.f, 0.f};
    d[j] = (floatx2){0.f, 0.f}; e[j] = (floatx2){0.f, 0.f};
  }
  int i = 0;
  for (; i + 8 <= c; i += 8) {
    int s0 = csr[start + i + half];
    int s1 = csr[start + i + 2 + half];
    int s2 = csr[start + i + 4 + half];
    int s3 = csr[start + i + 6 + half];
    uint2 v0 = xq[(size_t)s0 * 32 + l32];
    uint2 v1 = xq[(size_t)s1 * 32 + l32];
    uint2 v2 = xq[(size_t)s2 * 32 + l32];
    uint2 v3 = xq[(size_t)s3 * 32 + l32];
    acc8p(v0, a); acc8p(v1, b); acc8p(v2, d); acc8p(v3, e);
  }
  for (; i + 2 <= c; i += 2) {
    int s0 = csr[start + i + half];
    uint2 v0 = xq[(size_t)s0 * 32 + l32];
    acc8p(v0, a);
  }
  if ((c & 1) && half == 0) {
    int s0 = csr[start + c - 1];
    uint2 v0 = xq[(size_t)s0 * 32 + l32];
    acc8p(v0, a);
  }
#pragma unroll
  for (int j = 0; j < 4; j++) a[j] += b[j] + d[j] + e[j];

  float f[8];
#pragma unroll
  for (int j = 0; j < 4; j++) { f[2 * j] = a[j].x; f[2 * j + 1] = a[j].y; }
#pragma unroll
  for (int j = 0; j < 8; j++) f[j] += __shfl_xor(f[j], 32);

  if (half == 0) {
    float inv = 1.0f / fmaxf((float)c, 1.0f);
#pragma unroll
    for (int j = 0; j < 8; j++) f[j] *= inv;
    int lo0 = __builtin_amdgcn_cvt_pk_fp8_f32(f[0], f[1], 0, false);
    int w0  = __builtin_amdgcn_cvt_pk_fp8_f32(f[2], f[3], lo0, true);
    int lo1 = __builtin_amdgcn_cvt_pk_fp8_f32(f[4], f[5], 0, false);
    int w1  = __builtin_amdgcn_cvt_pk_fp8_f32(f[6], f[7], lo1, true);
    aggq[(size_t)wid * 32 + l32] = make_uint2((unsigned)w0, (unsigned)w1);
  }
}

// ---------------------------------------------------------------------------
// k_h: gsum[c] += sum_rows relu( [x|agg] @ W + b )  -- wave-independent GEMM,
// occupancy-tuned. Each wave owns 32 rows x 128 cols (4 x 32x32x16 MFMA
// col-tiles, 64 acc regs). Block = 4 waves as 2 row-strips x 2 col-halves.
// A: 8 fp8 bytes/lane direct global->VGPR, decoded to bf16 (exact).
// B: fragment-linear, 1 KB coalesced wave loads from L2-resident 256 KB.
// No LDS staging, no K-loop barriers; __launch_bounds__(256,4) -> 16 waves/CU.
// C/D: col=lane&31, row=(reg&3)+8*(reg>>2)+4*(lane>>5)  [m74/m101 verified]
// ---------------------------------------------------------------------------
__global__ __launch_bounds__(256, 4) void k_h(
    const unsigned char* __restrict__ xq8, const unsigned char* __restrict__ aggq8,
    const uint4* __restrict__ Bf, const float* __restrict__ bself,
    const float* __restrict__ bnei, float* __restrict__ gsum, int N) {
  __shared__ float colsum[256];
  int tid = threadIdx.x;
  int lane = tid & 63;
  int w = tid >> 6;
  int wr = w >> 1, wc = w & 1;
  int l32 = lane & 31;
  int half = lane >> 5;
  int rowBase = blockIdx.x * 64 + wr * 32;
  int row = rowBase + l32;
  if (row >= N) row = N - 1;

  colsum[tid] = 0.f;
  __syncthreads();

  floatx16 acc[4];
#pragma unroll
  for (int j = 0; j < 4; j++) acc[j] = (floatx16)(0.f);

  size_t aoff = (size_t)row * HID + half * 8;

#pragma unroll 2
  for (int c = 0; c < 32; c++) {
    const unsigned char* ab = (c < 16) ? xq8 : aggq8;
    uint2 va = *(const uint2*)(ab + aoff + (size_t)(c & 15) * 16);
    const uint4* bp = Bf + (size_t)c * 512 + wc * 256 + lane;
    uint4 b0 = bp[0];
    uint4 b1 = bp[64];
    uint4 b2 = bp[128];
    uint4 b3 = bp[192];
    short8 af = dec8(va);
    acc[0] = __builtin_amdgcn_mfma_f32_32x32x16_bf16(af, u4_s8(b0), acc[0], 0, 0, 0);
    acc[1] = __builtin_amdgcn_mfma_f32_32x32x16_bf16(af, u4_s8(b1), acc[1], 0, 0, 0);
    acc[2] = __builtin_amdgcn_mfma_f32_32x32x16_bf16(af, u4_s8(b2), acc[2], 0, 0, 0);
    acc[3] = __builtin_amdgcn_mfma_f32_32x32x16_bf16(af, u4_s8(b3), acc[3], 0, 0, 0);
  }

  // epilogue: bias + relu + row-masked column sums
#pragma unroll
  for (int ct = 0; ct < 4; ct++) {
    int col = wc * 128 + ct * 32 + l32;
    float bb = bself[col] + bnei[col];
    float psum = 0.f;
#pragma unroll
    for (int r = 0; r < 16; r++) {
      int rw = rowBase + (r & 3) + 8 * (r >> 2) + 4 * half;
      float v = acc[ct][r] + bb;
      v = v > 0.f ? v : 0.f;
      if (rw < N) psum += v;
    }
    atomicAdd(&colsum[col], psum);
  }
  __syncthreads();
  atomicAdd(&gsum[tid], colsum[tid]);
}

// ---------------------------------------------------------------------------
// k_out: out = (gsum / N) @ W_out + b_out   single block, 256 threads
// ---------------------------------------------------------------------------
__global__ __launch_bounds__(HID) void k_out(
    const float* __restrict__ gsum, const float* __restrict__ Wout,
    const float* __restrict__ bout, float* __restrict__ out, float invN) {
  __shared__ float g[HID];
  int c = threadIdx.x;
  g[c] = gsum[c] * invN;
  __syncthreads();
  float acc = bout[c];
#pragma unroll 8
  for (int k = 0; k < HID; k++) acc += g[k] * Wout[k * HID + c];
  out[c] = acc;
}

extern "C" void kernel_launch(void* const* d_in, const int* in_sizes, int n_in,
                              void* d_out, int out_size, void* d_ws, size_t ws_size,
                              hipStream_t stream) {
  const float* ns    = (const float*)d_in[0];
  const float* Win   = (const float*)d_in[1];
  const float* bin   = (const float*)d_in[2];
  const float* Wself = (const float*)d_in[3];
  const float* bself = (const float*)d_in[4];
  const float* Wnei  = (const float*)d_in[5];
  const float* bnei  = (const float*)d_in[6];
  const float* Wout  = (const float*)d_in[7];
  const float* bout  = (const float*)d_in[8];
  const int*   eidx  = (const int*)d_in[9];

  int N = in_sizes[0] / IND;
  int E = in_sizes[9] / 2;
  const int* src = eidx;
  const int* dst = eidx + E;
  int nb2 = (N + 255) >> 8;

  // ws layout: xq[N*64] uint | aggq[N*64] uint | Bf[32*8*64] uint4 (256 KB) |
  //   csr[E] i | ebuf[E] uint | row_start[N+1] i | bcnt | bbase | bcur | gsum
  unsigned int* xq    = (unsigned int*)d_ws;
  unsigned int* aggq  = xq + (size_t)N * 64;
  unsigned short* Bf16 = (unsigned short*)(aggq + (size_t)N * 64);
  int* csr       = (int*)(Bf16 + 256 * 512);
  unsigned int* ebuf = (unsigned int*)(csr + E);
  int* row_start = (int*)(ebuf + E);
  int* bcnt      = row_start + N + 1;
  int* bbase     = bcnt + MAXB;
  int* bcur      = bbase + MAXB + 1;
  float* gsum    = (float*)(bcur + MAXB);

  hipMemsetAsync(bcnt, 0, MAXB * sizeof(int), stream);
  hipMemsetAsync(gsum, 0, HID * sizeof(float), stream);

  int G1 = (N + 7) / 8;
  int pgrid = (E + PB - 1) / PB;
  k_front<<<G1 + 256 + pgrid, 256, 0, stream>>>(
      ns, Win, bin, xq, Wself, Wnei, Bf16, dst, bcnt, N, E, nb2, G1);

  k_bscan<<<1, 512, 0, stream>>>(bcnt, bbase, bcur, row_start, E, N, nb2);
  k_part<<<pgrid, 256, 0, stream>>>(src, dst, bcur, ebuf, E, nb2);
  k_fill2<<<nb2, 256, 0, stream>>>(ebuf, bbase, row_start, csr, N);

  int agrid = (N + 3) / 4;
  k_agg<<<agrid, 256, 0, stream>>>((const uint2*)xq, csr, row_start,
                                   (uint2*)aggq, N);

  int hgrid = (N + 63) / 64;
  k_h<<<hgrid, 256, 0, stream>>>((const unsigned char*)xq,
                                 (const unsigned char*)aggq,
                                 (const uint4*)Bf16, bself, bnei, gsum, N);

  k_out<<<1, HID, 0, stream>>>(gsum, Wout, bout, (float*)d_out, 1.0f / (float)N);
}

// Round 12
// 314.050 us; speedup vs baseline: 1.0996x; 1.0953x over previous
//
#include <hip/hip_runtime.h>
#include <hip/hip_bf16.h>

#define HID 256
#define IND 21
#define PB 6400      // edges per block in k_part / bhist
#define MAXB 512     // max buckets (N <= 131072)
#define AST 72       // A LDS row stride BYTES (64 fp8 + 8 pad): 2-way banks only

typedef short short8 __attribute__((ext_vector_type(8)));
typedef float floatx16 __attribute__((ext_vector_type(16)));
typedef float floatx2 __attribute__((ext_vector_type(2)));

__device__ inline unsigned short f2bf(float f) {
  __hip_bfloat16 h = __float2bfloat16(f);  // RNE
  union { __hip_bfloat16 h; unsigned short u; } c;
  c.h = h;
  return c.u;
}

// pack float2 -> 2 bf16 by truncation (exact for values that came from fp8)
__device__ inline unsigned int pk_bf16_trunc(floatx2 p) {
  union { float f; unsigned int u; } a, b;
  a.f = p.x; b.f = p.y;
  return (b.u & 0xffff0000u) | (a.u >> 16);
}

// accumulate 8 fp8 bytes into 4 packed-f32 accumulators
__device__ inline void acc8p(uint2 v, floatx2* a) {
  a[0] += __builtin_amdgcn_cvt_pk_f32_fp8((int)v.x, false);
  a[1] += __builtin_amdgcn_cvt_pk_f32_fp8((int)v.x, true);
  a[2] += __builtin_amdgcn_cvt_pk_f32_fp8((int)v.y, false);
  a[3] += __builtin_amdgcn_cvt_pk_f32_fp8((int)v.y, true);
}

__device__ inline short8 mk_s8(unsigned a, unsigned b, unsigned c, unsigned d) {
  union { uint4 u; short8 s; } x; x.u = make_uint4(a, b, c, d); return x.s;
}

// decode 8 fp8 bytes (uint2) -> short8 of bf16 (exact)
__device__ inline short8 dec8(uint2 v) {
  unsigned w0 = pk_bf16_trunc(__builtin_amdgcn_cvt_pk_f32_fp8((int)v.x, false));
  unsigned w1 = pk_bf16_trunc(__builtin_amdgcn_cvt_pk_f32_fp8((int)v.x, true));
  unsigned w2 = pk_bf16_trunc(__builtin_amdgcn_cvt_pk_f32_fp8((int)v.y, false));
  unsigned w3 = pk_bf16_trunc(__builtin_amdgcn_cvt_pk_f32_fp8((int)v.y, true));
  return mk_s8(w0, w1, w2, w3);
}

// ---------------------------------------------------------------------------
// fused front kernel: [0,G1) linear_in | [G1,G1+256) wconv | rest bhist
// wconv writes B in MFMA-fragment-linear order for 32x32x16:
//   Bf16[ ((c*8+ct)*64 + lane)*8 + j ] = W[k][n],
//   k = c*16 + (lane>>5)*8 + j, n = ct*32 + (lane&31)
// ---------------------------------------------------------------------------
__global__ __launch_bounds__(256) void k_front(
    const float* __restrict__ ns, const float* __restrict__ Win,
    const float* __restrict__ bin, unsigned int* __restrict__ xq,
    const float* __restrict__ Wself, const float* __restrict__ Wnei,
    unsigned short* __restrict__ Bf16,
    const int* __restrict__ dst, int* __restrict__ bcnt,
    int N, int E, int nb2, int G1) {
  int blk = blockIdx.x;
  int tid = threadIdx.x;
  if (blk < G1) {
    __shared__ float s[8][IND];
    __shared__ float fx[8][257];
    int nb = blk * 8;
    if (tid < 8 * IND) {
      int idx = nb * IND + tid;
      s[tid / IND][tid % IND] = (idx < N * IND) ? ns[idx] : 0.f;
    }
    float w[IND];
#pragma unroll
    for (int k = 0; k < IND; k++) w[k] = Win[k * HID + tid];
    float b = bin[tid];
    __syncthreads();
#pragma unroll
    for (int j = 0; j < 8; j++) {
      float acc = b;
#pragma unroll
      for (int k = 0; k < IND; k++) acc += s[j][k] * w[k];
      fx[j][tid] = acc > 0.f ? acc : 0.f;
    }
    __syncthreads();
#pragma unroll
    for (int t = 0; t < 2; t++) {
      int wi = tid + t * 256;
      int j = wi >> 6, cw = wi & 63;
      int node = nb + j;
      if (node < N) {
        const float* fp = &fx[j][cw * 4];
        int lo = __builtin_amdgcn_cvt_pk_fp8_f32(fp[0], fp[1], 0, false);
        int full = __builtin_amdgcn_cvt_pk_fp8_f32(fp[2], fp[3], lo, true);
        xq[(size_t)node * 64 + cw] = (unsigned int)full;
      }
    }
  } else if (blk < G1 + 256) {
    int n = blk - G1;           // output column 0..255
    int ct = n >> 5, l5 = n & 31;
#pragma unroll
    for (int t = 0; t < 2; t++) {
      int k = tid + t * 256;    // 0..511
      float v = (k < HID) ? Wself[k * HID + n] : Wnei[(k - HID) * HID + n];
      int c = k >> 4, kin = k & 15;
      int lane = (kin >> 3) * 32 + l5;
      int j = kin & 7;
      Bf16[(size_t)((c * 8 + ct) * 64 + lane) * 8 + j] = f2bf(v);
    }
  } else {
    __shared__ int lh[MAXB];
    int e0 = (blk - G1 - 256) * PB;
    for (int b = tid; b < nb2; b += 256) lh[b] = 0;
    __syncthreads();
    int c = min(PB, E - e0);
    for (int i = tid; i < c; i += 256) atomicAdd(&lh[dst[e0 + i] >> 8], 1);
    __syncthreads();
    for (int b = tid; b < nb2; b += 256)
      if (lh[b]) atomicAdd(&bcnt[b], lh[b]);
  }
}

__global__ __launch_bounds__(512) void k_bscan(
    const int* __restrict__ bcnt, int* __restrict__ bbase, int* __restrict__ bcur,
    int* __restrict__ row_start, int E, int N, int nb2) {
  __shared__ int ts[512];
  int tid = threadIdx.x;
  int v = (tid < nb2) ? bcnt[tid] : 0;
  ts[tid] = v;
  __syncthreads();
  for (int off = 1; off < 512; off <<= 1) {
    int t = (tid >= off) ? ts[tid - off] : 0;
    __syncthreads();
    ts[tid] += t;
    __syncthreads();
  }
  if (tid < nb2) { bbase[tid] = ts[tid] - v; bcur[tid] = ts[tid] - v; }
  if (tid == 0) { bbase[nb2] = E; row_start[N] = E; }
}

// partition edges into per-bucket regions of ebuf (bucket = dst>>8).
// ebuf entry packed: (src << 8) | (dst & 255) -- 4 B/edge.
__global__ __launch_bounds__(256) void k_part(
    const int* __restrict__ src, const int* __restrict__ dst,
    int* __restrict__ bcur, unsigned int* __restrict__ ebuf, int E, int nb2) {
  __shared__ int lh[MAXB];
  int tid = threadIdx.x;
  int e0 = blockIdx.x * PB;
  for (int b = tid; b < nb2; b += 256) lh[b] = 0;
  __syncthreads();
  int cnt = min(PB, E - e0);
  for (int i = tid; i < cnt; i += 256) atomicAdd(&lh[dst[e0 + i] >> 8], 1);
  __syncthreads();
  for (int b = tid; b < nb2; b += 256) {
    int c = lh[b];
    lh[b] = (c > 0) ? atomicAdd(&bcur[b], c) : 0;
  }
  __syncthreads();
  for (int i = tid; i < cnt; i += 256) {
    int s = src[e0 + i];
    int d = dst[e0 + i];
    int pos = atomicAdd(&lh[d >> 8], 1);
    ebuf[pos] = ((unsigned)s << 8) | ((unsigned)d & 255u);
  }
}

// one block per bucket: LDS count + scan -> row_start; LDS cursors -> csr.
__global__ __launch_bounds__(256) void k_fill2(
    const unsigned int* __restrict__ ebuf, const int* __restrict__ bbase,
    int* __restrict__ row_start, int* __restrict__ csr, int N) {
  __shared__ int lcnt[256];
  __shared__ int lcur[256];
  __shared__ int ts[256];
  int b = blockIdx.x;
  int tid = threadIdx.x;
  int start = bbase[b], end = bbase[b + 1];
  lcnt[tid] = 0;
  __syncthreads();
  for (int i = start + tid; i < end; i += 256)
    atomicAdd(&lcnt[ebuf[i] & 255u], 1);
  __syncthreads();
  int v = lcnt[tid];
  ts[tid] = v;
  __syncthreads();
  for (int off = 1; off < 256; off <<= 1) {
    int t = (tid >= off) ? ts[tid - off] : 0;
    __syncthreads();
    ts[tid] += t;
    __syncthreads();
  }
  int excl = start + ts[tid] - v;
  int node = (b << 8) + tid;
  if (node < N) row_start[node] = excl;
  lcur[tid] = excl;
  __syncthreads();
  for (int i = start + tid; i < end; i += 256) {
    unsigned int e = ebuf[i];
    int pos = atomicAdd(&lcur[e & 255u], 1);
    csr[pos] = (int)(e >> 8);
  }
}

// ---------------------------------------------------------------------------
// k_agg: one wave per node; fp8 gather, 8 edges/iter, packed-f32 adds.
// ---------------------------------------------------------------------------
__global__ __launch_bounds__(256) void k_agg(
    const uint2* __restrict__ xq, const int* __restrict__ csr,
    const int* __restrict__ row_start, uint2* __restrict__ aggq, int N) {
  int wid = (int)((blockIdx.x * (unsigned)blockDim.x + threadIdx.x) >> 6);
  int lane = threadIdx.x & 63;
  int half = lane >> 5;
  int l32 = lane & 31;
  if (wid >= N) return;
  int start = row_start[wid];
  int end = row_start[wid + 1];
  int c = end - start;
  floatx2 a[4], b[4], d[4], e[4];
#pragma unroll
  for (int j = 0; j < 4; j++) {
    a[j] = (floatx2){0.f, 0.f}; b[j] = (floatx2){0.f, 0.f};
    d[j] = (floatx2){0.f, 0.f}; e[j] = (floatx2){0.f, 0.f};
  }
  int i = 0;
  for (; i + 8 <= c; i += 8) {
    int s0 = csr[start + i + half];
    int s1 = csr[start + i + 2 + half];
    int s2 = csr[start + i + 4 + half];
    int s3 = csr[start + i + 6 + half];
    uint2 v0 = xq[(size_t)s0 * 32 + l32];
    uint2 v1 = xq[(size_t)s1 * 32 + l32];
    uint2 v2 = xq[(size_t)s2 * 32 + l32];
    uint2 v3 = xq[(size_t)s3 * 32 + l32];
    acc8p(v0, a); acc8p(v1, b); acc8p(v2, d); acc8p(v3, e);
  }
  for (; i + 2 <= c; i += 2) {
    int s0 = csr[start + i + half];
    uint2 v0 = xq[(size_t)s0 * 32 + l32];
    acc8p(v0, a);
  }
  if ((c & 1) && half == 0) {
    int s0 = csr[start + c - 1];
    uint2 v0 = xq[(size_t)s0 * 32 + l32];
    acc8p(v0, a);
  }
#pragma unroll
  for (int j = 0; j < 4; j++) a[j] += b[j] + d[j] + e[j];

  float f[8];
#pragma unroll
  for (int j = 0; j < 4; j++) { f[2 * j] = a[j].x; f[2 * j + 1] = a[j].y; }
#pragma unroll
  for (int j = 0; j < 8; j++) f[j] += __shfl_xor(f[j], 32);

  if (half == 0) {
    float inv = 1.0f / fmaxf((float)c, 1.0f);
#pragma unroll
    for (int j = 0; j < 8; j++) f[j] *= inv;
    int lo0 = __builtin_amdgcn_cvt_pk_fp8_f32(f[0], f[1], 0, false);
    int w0  = __builtin_amdgcn_cvt_pk_fp8_f32(f[2], f[3], lo0, true);
    int lo1 = __builtin_amdgcn_cvt_pk_fp8_f32(f[4], f[5], 0, false);
    int w1  = __builtin_amdgcn_cvt_pk_fp8_f32(f[6], f[7], lo1, true);
    aggq[(size_t)wid * 32 + l32] = make_uint2((unsigned)w0, (unsigned)w1);
  }
}

// ---------------------------------------------------------------------------
// k_h: gsum[c] += sum_rows relu( [x|agg] @ W + b )  -- LDS-staged block GEMM.
// Block = 128 rows x 128 cols (gridDim.y=2 col-halves), 4 waves 2x2, wave
// tile 64x64 via 2x2 of mfma_f32_32x32x16_bf16 (acc = 64 VGPRs). BK=64,
// 8 chunks. A kept fp8 in LDS (stride 72 B, 2-way banks; dec8 at consume);
// B staged from fragment-linear Bf16 (lane-linear LDS, 2-way banks).
// Next chunk register-prefetched (6 uint4) during the MFMA phase.
// __launch_bounds__(256,3) -> 3 blocks/CU.
// C/D: col=lane&31, row=(reg&3)+8*(reg>>2)+4*(lane>>5)  [m74/m101 verified]
// ---------------------------------------------------------------------------
__global__ __launch_bounds__(256, 3) void k_h(
    const unsigned char* __restrict__ xq8, const unsigned char* __restrict__ aggq8,
    const unsigned short* __restrict__ Bf16, const float* __restrict__ bself,
    const float* __restrict__ bnei, float* __restrict__ gsum, int N) {
  __shared__ __align__(16) unsigned char As[128 * AST];   // 9 KB
  __shared__ __align__(16) unsigned short Bs[16 * 512];   // 16 KB
  __shared__ float colsum[128];
  int tid = threadIdx.x;
  int lane = tid & 63;
  int w = tid >> 6;
  int wr = w >> 1, wc = w & 1;
  int l32 = lane & 31, half = lane >> 5;
  int rowBase = blockIdx.x * 128;
  int by = blockIdx.y;            // 0/1: cols by*128 .. +128

  if (tid < 128) colsum[tid] = 0.f;

  floatx16 acc[2][2];
#pragma unroll
  for (int i = 0; i < 2; i++)
#pragma unroll
    for (int j = 0; j < 2; j++) acc[i][j] = (floatx16)(0.f);

  // A staging coords: thread t -> row t>>1, 32B half t&1
  int ar = tid >> 1;
  int ah = tid & 1;
  int gr = rowBase + ar;
  if (gr >= N) gr = N - 1;
  size_t abase = (size_t)gr * HID + ah * 32;

  // B staging coords: group bg = (cl, ctl), 16 threads each cover 1 KB group
  int bg = tid >> 4;              // 0..15
  int btl = tid & 15;
  int bcl = bg >> 2, bctl = bg & 3;
  // Bf16 short offset for chunk ch: ((ch*4+bcl)*8 + by*4 + bctl)*512 + btl*32
  size_t bstep = (size_t)(by * 4 + bctl) * 512 + (size_t)bcl * 8 * 512 + btl * 32;

  uint4 pa0, pa1, pb0, pb1, pb2, pb3;
  {
    pa0 = *(const uint4*)(xq8 + abase);
    pa1 = *(const uint4*)(xq8 + abase + 16);
    const unsigned short* bsrc = Bf16 + bstep;
    pb0 = *(const uint4*)(bsrc);
    pb1 = *(const uint4*)(bsrc + 8);
    pb2 = *(const uint4*)(bsrc + 16);
    pb3 = *(const uint4*)(bsrc + 24);
  }

  for (int ch = 0; ch < 8; ch++) {
    __syncthreads();   // prior chunk's consumers done
    // ---- write staged regs to LDS ----
    {
      unsigned char* ap = &As[ar * AST + ah * 32];
      *(uint2*)(ap + 0)  = make_uint2(pa0.x, pa0.y);
      *(uint2*)(ap + 8)  = make_uint2(pa0.z, pa0.w);
      *(uint2*)(ap + 16) = make_uint2(pa1.x, pa1.y);
      *(uint2*)(ap + 24) = make_uint2(pa1.z, pa1.w);
      unsigned short* bp = &Bs[bg * 512 + btl * 32];
      *(uint4*)(bp + 0)  = pb0;
      *(uint4*)(bp + 8)  = pb1;
      *(uint4*)(bp + 16) = pb2;
      *(uint4*)(bp + 24) = pb3;
    }
    __syncthreads();
    // ---- prefetch next chunk into regs (overlaps MFMA phase) ----
    if (ch < 7) {
      int cn = ch + 1;
      const unsigned char* ab = (cn < 4) ? xq8 : aggq8;
      int kc = (cn & 3) * 64;
      pa0 = *(const uint4*)(ab + abase + kc);
      pa1 = *(const uint4*)(ab + abase + kc + 16);
      const unsigned short* bsrc = Bf16 + (size_t)cn * 4 * 8 * 512 + bstep;
      pb0 = *(const uint4*)(bsrc);
      pb1 = *(const uint4*)(bsrc + 8);
      pb2 = *(const uint4*)(bsrc + 16);
      pb3 = *(const uint4*)(bsrc + 24);
    }
    // ---- MFMA phase: 4 K-steps of 16 ----
#pragma unroll
    for (int cl = 0; cl < 4; cl++) {
      short8 afr[2];
#pragma unroll
      for (int rt = 0; rt < 2; rt++) {
        uint2 av = *(const uint2*)&As[(wr * 64 + rt * 32 + l32) * AST + cl * 16 + half * 8];
        afr[rt] = dec8(av);
      }
#pragma unroll
      for (int ctw = 0; ctw < 2; ctw++) {
        int ctl = wc * 2 + ctw;
        short8 bfr = *(const short8*)&Bs[((cl * 4 + ctl) * 64 + lane) * 8];
#pragma unroll
        for (int rt = 0; rt < 2; rt++)
          acc[rt][ctw] = __builtin_amdgcn_mfma_f32_32x32x16_bf16(
              afr[rt], bfr, acc[rt][ctw], 0, 0, 0);
      }
    }
  }

  // epilogue: bias + relu + row-masked column sums
#pragma unroll
  for (int ctw = 0; ctw < 2; ctw++) {
    int lcol = (wc * 2 + ctw) * 32 + l32;
    int gcol = by * 128 + lcol;
    float bb = bself[gcol] + bnei[gcol];
    float psum[2] = {0.f, 0.f};
#pragma unroll
    for (int rt = 0; rt < 2; rt++) {
#pragma unroll
      for (int r = 0; r < 16; r++) {
        int rw = rowBase + wr * 64 + rt * 32 + (r & 3) + 8 * (r >> 2) + 4 * half;
        float v = acc[rt][ctw][r] + bb;
        v = v > 0.f ? v : 0.f;
        if (rw < N) psum[rt] += v;
      }
    }
    atomicAdd(&colsum[lcol], psum[0] + psum[1]);
  }
  __syncthreads();
  if (tid < 128) atomicAdd(&gsum[by * 128 + tid], colsum[tid]);
}

// ---------------------------------------------------------------------------
// k_out: out = (gsum / N) @ W_out + b_out   single block, 256 threads
// ---------------------------------------------------------------------------
__global__ __launch_bounds__(HID) void k_out(
    const float* __restrict__ gsum, const float* __restrict__ Wout,
    const float* __restrict__ bout, float* __restrict__ out, float invN) {
  __shared__ float g[HID];
  int c = threadIdx.x;
  g[c] = gsum[c] * invN;
  __syncthreads();
  float acc = bout[c];
#pragma unroll 8
  for (int k = 0; k < HID; k++) acc += g[k] * Wout[k * HID + c];
  out[c] = acc;
}

extern "C" void kernel_launch(void* const* d_in, const int* in_sizes, int n_in,
                              void* d_out, int out_size, void* d_ws, size_t ws_size,
                              hipStream_t stream) {
  const float* ns    = (const float*)d_in[0];
  const float* Win   = (const float*)d_in[1];
  const float* bin   = (const float*)d_in[2];
  const float* Wself = (const float*)d_in[3];
  const float* bself = (const float*)d_in[4];
  const float* Wnei  = (const float*)d_in[5];
  const float* bnei  = (const float*)d_in[6];
  const float* Wout  = (const float*)d_in[7];
  const float* bout  = (const float*)d_in[8];
  const int*   eidx  = (const int*)d_in[9];

  int N = in_sizes[0] / IND;
  int E = in_sizes[9] / 2;
  const int* src = eidx;
  const int* dst = eidx + E;
  int nb2 = (N + 255) >> 8;

  // ws layout: xq[N*64] uint | aggq[N*64] uint | Bf16[32*8*64*8] bf16 (256 KB) |
  //   csr[E] i | ebuf[E] uint | row_start[N+1] i | bcnt | bbase | bcur | gsum
  unsigned int* xq    = (unsigned int*)d_ws;
  unsigned int* aggq  = xq + (size_t)N * 64;
  unsigned short* Bf16 = (unsigned short*)(aggq + (size_t)N * 64);
  int* csr       = (int*)(Bf16 + 256 * 512);
  unsigned int* ebuf = (unsigned int*)(csr + E);
  int* row_start = (int*)(ebuf + E);
  int* bcnt      = row_start + N + 1;
  int* bbase     = bcnt + MAXB;
  int* bcur      = bbase + MAXB + 1;
  float* gsum    = (float*)(bcur + MAXB);

  hipMemsetAsync(bcnt, 0, MAXB * sizeof(int), stream);
  hipMemsetAsync(gsum, 0, HID * sizeof(float), stream);

  int G1 = (N + 7) / 8;
  int pgrid = (E + PB - 1) / PB;
  k_front<<<G1 + 256 + pgrid, 256, 0, stream>>>(
      ns, Win, bin, xq, Wself, Wnei, Bf16, dst, bcnt, N, E, nb2, G1);

  k_bscan<<<1, 512, 0, stream>>>(bcnt, bbase, bcur, row_start, E, N, nb2);
  k_part<<<pgrid, 256, 0, stream>>>(src, dst, bcur, ebuf, E, nb2);
  k_fill2<<<nb2, 256, 0, stream>>>(ebuf, bbase, row_start, csr, N);

  int agrid = (N + 3) / 4;
  k_agg<<<agrid, 256, 0, stream>>>((const uint2*)xq, csr, row_start,
                                   (uint2*)aggq, N);

  dim3 hgrid((N + 127) / 128, 2);
  k_h<<<hgrid, 256, 0, stream>>>((const unsigned char*)xq,
                                 (const unsigned char*)aggq,
                                 Bf16, bself, bnei, gsum, N);

  k_out<<<1, HID, 0, stream>>>(gsum, Wout, bout, (float*)d_out, 1.0f / (float)N);
}